// Round 14
// baseline (207.601 us; speedup 1.0000x reference)
//
#include <hip/hip_runtime.h>
#include <hip/hip_bf16.h>
#include <math.h>
#include <stdint.h>

#define NROWS 1000000
#define NCOLS 100
#define NBINS 20
#define NB    19       // bin boundaries
#define W     50000u   // rows per bin
#define NH    2049     // buckets: 0 = catch-all (<0.5), 1..2048 = [0.5,1) in 2^-12 steps
#define CBASE 1921     // first bucket held in k1's LDS hist cache (top 128)

// ---------- ws layout (dword offsets) ----------
#define HIST_DW 0u       // len 2052
#define BINS_DW 2052u    // len 80 dw = 40 doubles (byte 8208, 8-aligned)
#define ZERO_DW 2132u    // hist+bins zeroed by k0
#define CONF_DW 2136u    // len 1000000 (byte 8544 = 534*16, 16B-aligned); sign bit = accuracy

__device__ __forceinline__ unsigned int bucket_of(unsigned int bits) {
    // bits = positive-f32 pattern. conf < 0.5 -> 0 (catch-all).
    if (bits < 0x3F000000u) return 0u;
    unsigned int t = (bits >> 12) - 258048u + 1u;   // 1..2048 for [0.5,1)
    return t > 2048u ? 2048u : t;
}

// ---------- K0: zero hist + bins (k1 accumulates hist -> can't self-zero) --
__global__ __launch_bounds__(256) void k0_zero(unsigned int* __restrict__ wd) {
    unsigned int i = blockIdx.x * 256 + threadIdx.x;
    if (i < ZERO_DW) wd[i] = 0u;
}

// ---------- K1: LDS-staged row max/argmax + fused histogram ----------------
// r13 post-mortem: NT loads were the -80us regression (nt policy defeats
// L2 read-combining on this stream). Reverted to PLAIN float4 loads (the
// r9/r10 proven 84us staging). Kept: fused epilogue histogram (top-128
// buckets in 512B LDS cache ~96% of values, cold 4% direct global
// atomics, one flush per block) — k2 stays deleted.
__global__ __launch_bounds__(256) void k1_rowmax(const float* __restrict__ x,
                                                 const int* __restrict__ labels,
                                                 float* __restrict__ conf,
                                                 unsigned int* __restrict__ hist) {
    __shared__ float4 ldsx4[1600];                 // 64 rows x 25 float4, linear
    __shared__ unsigned long long ldsk[64];
    __shared__ unsigned int lcache[128];           // buckets CBASE..2048
    const float* ldsx = (const float*)ldsx4;
    int tid = threadIdx.x;
    if (tid < 128) lcache[tid] = 0u;               // visible by first epilogue (barrier below)

    const int NTILES = NROWS / 64;  // 15625
    const float4* xb = reinterpret_cast<const float4*>(x);
    for (int tile = blockIdx.x; tile < NTILES; tile += gridDim.x) {
        // --- stage: 1600 float4 = 64 rows, dense coalesced ---
        const float4* src = xb + (size_t)tile * 1600;
        #pragma unroll
        for (int i = 0; i < 7; i++) {
            int v = i * 256 + tid;
            if (v < 1600) ldsx4[v] = src[v];
        }
        if (tid < 64) ldsk[tid] = 0ull;
        __syncthreads();
        // --- reduce: thread = (row r, quarter q); dword addr = 25*tid+k ---
        int r = tid >> 2, q = tid & 3;
        const float* rowp = ldsx + r * 100 + q * 25;
        float best = rowp[0]; int bi = 0;
        #pragma unroll
        for (int k = 1; k < 25; k++) {
            float vv = rowp[k];
            if (vv > best) { best = vv; bi = k; }
        }
        unsigned long long key =
            ((unsigned long long)__float_as_uint(best) << 32)
            | (unsigned int)(NCOLS - (q * 25 + bi));   // bigger low32 = smaller idx
        atomicMax(&ldsk[r], key);
        __syncthreads();
        if (tid < 64) {
            unsigned long long kk = ldsk[tid];
            unsigned int bits = (unsigned int)(kk >> 32);
            int idx = NCOLS - (int)(kk & 0xFFFFFFFFu);
            int row = tile * 64 + tid;
            // histogram (positive pattern, before sign-packing)
            unsigned int b = bucket_of(bits);
            int ci = (int)b - CBASE;
            if (ci >= 0) atomicAdd(&lcache[ci], 1u);
            else         atomicAdd(&hist[b], 1u);
            if (idx == labels[row]) bits |= 0x80000000u;
            conf[row] = __uint_as_float(bits);
        }
        __syncthreads();   // ldsx/ldsk reused next tile (also orders lcache)
    }
    // --- flush LDS hist cache (loop-end barrier ordered all epilogues) ---
    if (tid < 128) {
        unsigned int c = lcache[tid];
        if (c) atomicAdd(&hist[CBASE + tid], c);
    }
}

// ---------- K3: per-block redundant scan+bounds, then split-accumulate ----
__global__ __launch_bounds__(256) void k3_accum(const float* __restrict__ conf,
                                                const unsigned int* __restrict__ hist,
                                                double* __restrict__ bins) {
    __shared__ unsigned int ptab[NH];   // prefix, later |= (slot+1)<<24 on boundary buckets
    __shared__ unsigned int s[256];
    __shared__ unsigned int bndS[NB];
    __shared__ float sFr[NB];
    __shared__ float sc[4][NBINS], sa[4][NBINS];
    int tid = threadIdx.x;

    // --- scan hist (2049) into ptab ---
    unsigned int loc[9];
    unsigned int tot = 0;
    int base = tid * 9;
    #pragma unroll
    for (int k = 0; k < 9; k++) {
        int idx = base + k;
        unsigned int v = (idx < NH) ? hist[idx] : 0u;
        loc[k] = tot; tot += v;
    }
    s[tid] = tot; __syncthreads();
    for (int off = 1; off < 256; off <<= 1) {
        unsigned int v = (tid >= off) ? s[tid - off] : 0u;
        __syncthreads();
        s[tid] += v;
        __syncthreads();
    }
    unsigned int excl = s[tid] - tot;
    #pragma unroll
    for (int k = 0; k < 9; k++) {
        int idx = base + k;
        if (idx < NH) ptab[idx] = excl + loc[k];
    }
    for (int i = tid; i < 4 * NBINS; i += 256) { (&sc[0][0])[i] = 0.f; (&sa[0][0])[i] = 0.f; }
    __syncthreads();

    // --- phase A: locate boundaries on the CLEAN prefix, save fr ---
    if (tid < NB) {
        unsigned int r = (unsigned int)(tid + 1) * W;
        int lo = 0, hi = NH - 1;
        while (lo < hi) {
            int mid = (lo + hi + 1) >> 1;
            if (ptab[mid] <= r) lo = mid; else hi = mid - 1;
        }
        unsigned int p = ptab[lo];
        if (p < r) {
            unsigned int cnt = ((lo + 1 < NH) ? ptab[lo + 1] : (unsigned int)NROWS) - p;
            bndS[tid] = (unsigned int)lo;
            sFr[tid]  = (float)(r - p) / (float)cnt;
        } else {
            bndS[tid] = 0xFFFFFFFFu;
        }
    }
    __syncthreads();
    // --- phase B: mark boundary buckets ---
    if (tid < NB && bndS[tid] != 0xFFFFFFFFu)
        ptab[bndS[tid]] |= (unsigned int)(tid + 1) << 24;
    __syncthreads();

    // --- main pass ---
    int wid = tid >> 6;
    const uint4* c4 = reinterpret_cast<const uint4*>(conf);
    int stride = gridDim.x * 256;
    for (int i = blockIdx.x * 256 + tid; i < NROWS / 4; i += stride) {
        uint4 q = c4[i];
        unsigned int bs[4] = { q.x, q.y, q.z, q.w };
        #pragma unroll
        for (int j = 0; j < 4; j++) {
            unsigned int raw = bs[j];
            float a = (float)(raw >> 31);
            unsigned int bits = raw & 0x7FFFFFFFu;
            float c = __uint_as_float(bits);
            unsigned int e = ptab[bucket_of(bits)];
            unsigned int t = e >> 24;
            if (t == 0u) {
                unsigned int bin = (e & 0xFFFFFFu) / W;
                atomicAdd(&sc[wid][bin], c); atomicAdd(&sa[wid][bin], a);
            } else {
                float fr = sFr[t - 1];
                atomicAdd(&sc[wid][t - 1], c * fr);
                atomicAdd(&sc[wid][t],     c * (1.f - fr));
                atomicAdd(&sa[wid][t - 1], a * fr);
                atomicAdd(&sa[wid][t],     a * (1.f - fr));
            }
        }
    }
    __syncthreads();
    if (tid < NBINS) {
        float tc = sc[0][tid] + sc[1][tid] + sc[2][tid] + sc[3][tid];
        float ta = sa[0][tid] + sa[1][tid] + sa[2][tid] + sa[3][tid];
        atomicAdd(&bins[tid],         (double)tc);
        atomicAdd(&bins[NBINS + tid], (double)ta);
    }
}

// ---------- K4: finalize ----------
__global__ __launch_bounds__(64) void k4_final(const double* __restrict__ bins,
                                               float* __restrict__ out) {
    if (threadIdx.x == 0) {
        double ece = 0.0;
        for (int b = 0; b < NBINS; b++) {
            double avc = bins[b] / (double)W;
            double ava = bins[NBINS + b] / (double)W;
            ece += fabs(avc - ava);
            out[1 + b] = (float)ava;
        }
        out[0] = (float)(ece * ((double)W / (double)NROWS));
    }
}

extern "C" void kernel_launch(void* const* d_in, const int* in_sizes, int n_in,
                              void* d_out, int out_size, void* d_ws, size_t ws_size,
                              hipStream_t stream) {
    const float* x      = (const float*)d_in[0];
    const int*   labels = (const int*)d_in[1];
    float*       out    = (float*)d_out;
    unsigned int* wd    = (unsigned int*)d_ws;

    unsigned int* hist = wd + HIST_DW;
    double*       bins = (double*)(wd + BINS_DW);
    float*        conf = (float*)(wd + CONF_DW);

    k0_zero  <<<9, 256, 0, stream>>>(wd);
    k1_rowmax<<<2048, 256, 0, stream>>>(x, labels, conf, hist);
    k3_accum <<<512, 256, 0, stream>>>(conf, hist, bins);
    k4_final <<<1, 64, 0, stream>>>(bins, out);
}

// Round 15
// 124.322 us; speedup vs baseline: 1.6699x; 1.6699x over previous
//
#include <hip/hip_runtime.h>
#include <hip/hip_bf16.h>
#include <math.h>
#include <stdint.h>

#define NROWS 1000000
#define NCOLS 100
#define NBINS 20
#define NB    19       // bin boundaries
#define W     50000u   // rows per bin
#define NH    2049     // buckets: 0 = catch-all (<0.5), 1..2048 = [0.5,1) in 2^-12 steps

// ---------- ws layout (dword offsets) ----------
#define HIST_DW 0u       // len 2052
#define BINS_DW 2052u    // len 80 dw = 40 doubles (byte 8208, 8-aligned)
#define ZERO_DW 2132u    // hist+bins zeroed inside k1
#define CONF_DW 2136u    // len 1000000 (byte 8544 = 534*16, 16B-aligned); sign bit = accuracy

__device__ __forceinline__ unsigned int bucket_of(unsigned int bits) {
    // bits = positive-f32 pattern. conf < 0.5 -> 0 (catch-all).
    if (bits < 0x3F000000u) return 0u;
    unsigned int t = (bits >> 12) - 258048u + 1u;   // 1..2048 for [0.5,1)
    return t > 2048u ? 2048u : t;
}

// ---------- K1: LDS-staged row max/argmax (r10 proven) + labels prefetch ---
// r14 post-mortem: fused-hist epilogue was the +82us regression (global
// atomic completion waited at every loop-bottom barrier) — reverted to the
// exact r10 structure (125.5us best). One change: labels[] for the tile is
// loaded DURING staging (before the first barrier) so its ~900cy cold-load
// latency hides under the 25.6KB stage drain instead of sitting serially
// in the per-tile epilogue.
__global__ __launch_bounds__(256) void k1_rowmax(const float* __restrict__ x,
                                                 const int* __restrict__ labels,
                                                 float* __restrict__ conf,
                                                 unsigned int* __restrict__ zero_region) {
    __shared__ float4 ldsx4[1600];                 // 64 rows x 25 float4, linear
    __shared__ unsigned long long ldsk[64];
    const float* ldsx = (const float*)ldsx4;
    int tid = threadIdx.x;
    int gtid = blockIdx.x * 256 + tid;
    if (gtid < (int)ZERO_DW) zero_region[gtid] = 0u;   // hist + bins

    const int NTILES = NROWS / 64;  // 15625
    const float4* xb = reinterpret_cast<const float4*>(x);
    for (int tile = blockIdx.x; tile < NTILES; tile += gridDim.x) {
        // --- stage: 1600 float4 = 64 rows, dense coalesced + labels issue ---
        const float4* src = xb + (size_t)tile * 1600;
        int lab = 0;
        if (tid < 64) lab = labels[tile * 64 + tid];   // issued with staging loads
        #pragma unroll
        for (int i = 0; i < 7; i++) {
            int v = i * 256 + tid;
            if (v < 1600) ldsx4[v] = src[v];
        }
        if (tid < 64) ldsk[tid] = 0ull;
        __syncthreads();
        // --- reduce: thread = (row r, quarter q); dword addr = 25*tid+k ---
        int r = tid >> 2, q = tid & 3;
        const float* rowp = ldsx + r * 100 + q * 25;
        float best = rowp[0]; int bi = 0;
        #pragma unroll
        for (int k = 1; k < 25; k++) {
            float vv = rowp[k];
            if (vv > best) { best = vv; bi = k; }
        }
        unsigned long long key =
            ((unsigned long long)__float_as_uint(best) << 32)
            | (unsigned int)(NCOLS - (q * 25 + bi));   // bigger low32 = smaller idx
        atomicMax(&ldsk[r], key);
        __syncthreads();
        if (tid < 64) {
            unsigned long long kk = ldsk[tid];
            unsigned int bits = (unsigned int)(kk >> 32);
            int idx = NCOLS - (int)(kk & 0xFFFFFFFFu);
            if (idx == lab) bits |= 0x80000000u;
            conf[tile * 64 + tid] = __uint_as_float(bits);
        }
        __syncthreads();   // ldsx/ldsk reused next tile
    }
}

// ---------- K2: 2049-bucket histogram, per-block LDS ----------
__global__ __launch_bounds__(512) void k2_hist(const float* __restrict__ conf,
                                               unsigned int* __restrict__ hist) {
    __shared__ unsigned int lh[NH];
    for (int i = threadIdx.x; i < NH; i += 512) lh[i] = 0u;
    __syncthreads();
    const uint4* c4 = reinterpret_cast<const uint4*>(conf);
    int stride = gridDim.x * 512;
    for (int i = blockIdx.x * 512 + threadIdx.x; i < NROWS / 4; i += stride) {
        uint4 v = c4[i];
        atomicAdd(&lh[bucket_of(v.x & 0x7FFFFFFFu)], 1u);
        atomicAdd(&lh[bucket_of(v.y & 0x7FFFFFFFu)], 1u);
        atomicAdd(&lh[bucket_of(v.z & 0x7FFFFFFFu)], 1u);
        atomicAdd(&lh[bucket_of(v.w & 0x7FFFFFFFu)], 1u);
    }
    __syncthreads();
    for (int i = threadIdx.x; i < NH; i += 512) {
        unsigned int c = lh[i];
        if (c) atomicAdd(&hist[i], c);
    }
}

// ---------- K3: per-block redundant scan+bounds, then split-accumulate ----
__global__ __launch_bounds__(256) void k3_accum(const float* __restrict__ conf,
                                                const unsigned int* __restrict__ hist,
                                                double* __restrict__ bins) {
    __shared__ unsigned int ptab[NH];   // prefix, later |= (slot+1)<<24 on boundary buckets
    __shared__ unsigned int s[256];
    __shared__ unsigned int bndS[NB];
    __shared__ float sFr[NB];
    __shared__ float sc[4][NBINS], sa[4][NBINS];
    int tid = threadIdx.x;

    // --- scan hist (2049) into ptab ---
    unsigned int loc[9];
    unsigned int tot = 0;
    int base = tid * 9;
    #pragma unroll
    for (int k = 0; k < 9; k++) {
        int idx = base + k;
        unsigned int v = (idx < NH) ? hist[idx] : 0u;
        loc[k] = tot; tot += v;
    }
    s[tid] = tot; __syncthreads();
    for (int off = 1; off < 256; off <<= 1) {
        unsigned int v = (tid >= off) ? s[tid - off] : 0u;
        __syncthreads();
        s[tid] += v;
        __syncthreads();
    }
    unsigned int excl = s[tid] - tot;
    #pragma unroll
    for (int k = 0; k < 9; k++) {
        int idx = base + k;
        if (idx < NH) ptab[idx] = excl + loc[k];
    }
    for (int i = tid; i < 4 * NBINS; i += 256) { (&sc[0][0])[i] = 0.f; (&sa[0][0])[i] = 0.f; }
    __syncthreads();

    // --- phase A: locate boundaries on the CLEAN prefix, save fr ---
    if (tid < NB) {
        unsigned int r = (unsigned int)(tid + 1) * W;
        int lo = 0, hi = NH - 1;
        while (lo < hi) {
            int mid = (lo + hi + 1) >> 1;
            if (ptab[mid] <= r) lo = mid; else hi = mid - 1;
        }
        unsigned int p = ptab[lo];
        if (p < r) {
            unsigned int cnt = ((lo + 1 < NH) ? ptab[lo + 1] : (unsigned int)NROWS) - p;
            bndS[tid] = (unsigned int)lo;
            sFr[tid]  = (float)(r - p) / (float)cnt;
        } else {
            bndS[tid] = 0xFFFFFFFFu;
        }
    }
    __syncthreads();
    // --- phase B: mark boundary buckets ---
    if (tid < NB && bndS[tid] != 0xFFFFFFFFu)
        ptab[bndS[tid]] |= (unsigned int)(tid + 1) << 24;
    __syncthreads();

    // --- main pass ---
    int wid = tid >> 6;
    const uint4* c4 = reinterpret_cast<const uint4*>(conf);
    int stride = gridDim.x * 256;
    for (int i = blockIdx.x * 256 + tid; i < NROWS / 4; i += stride) {
        uint4 q = c4[i];
        unsigned int bs[4] = { q.x, q.y, q.z, q.w };
        #pragma unroll
        for (int j = 0; j < 4; j++) {
            unsigned int raw = bs[j];
            float a = (float)(raw >> 31);
            unsigned int bits = raw & 0x7FFFFFFFu;
            float c = __uint_as_float(bits);
            unsigned int e = ptab[bucket_of(bits)];
            unsigned int t = e >> 24;
            if (t == 0u) {
                unsigned int bin = (e & 0xFFFFFFu) / W;
                atomicAdd(&sc[wid][bin], c); atomicAdd(&sa[wid][bin], a);
            } else {
                float fr = sFr[t - 1];
                atomicAdd(&sc[wid][t - 1], c * fr);
                atomicAdd(&sc[wid][t],     c * (1.f - fr));
                atomicAdd(&sa[wid][t - 1], a * fr);
                atomicAdd(&sa[wid][t],     a * (1.f - fr));
            }
        }
    }
    __syncthreads();
    if (tid < NBINS) {
        float tc = sc[0][tid] + sc[1][tid] + sc[2][tid] + sc[3][tid];
        float ta = sa[0][tid] + sa[1][tid] + sa[2][tid] + sa[3][tid];
        atomicAdd(&bins[tid],         (double)tc);
        atomicAdd(&bins[NBINS + tid], (double)ta);
    }
}

// ---------- K4: finalize ----------
__global__ __launch_bounds__(64) void k4_final(const double* __restrict__ bins,
                                               float* __restrict__ out) {
    if (threadIdx.x == 0) {
        double ece = 0.0;
        for (int b = 0; b < NBINS; b++) {
            double avc = bins[b] / (double)W;
            double ava = bins[NBINS + b] / (double)W;
            ece += fabs(avc - ava);
            out[1 + b] = (float)ava;
        }
        out[0] = (float)(ece * ((double)W / (double)NROWS));
    }
}

extern "C" void kernel_launch(void* const* d_in, const int* in_sizes, int n_in,
                              void* d_out, int out_size, void* d_ws, size_t ws_size,
                              hipStream_t stream) {
    const float* x      = (const float*)d_in[0];
    const int*   labels = (const int*)d_in[1];
    float*       out    = (float*)d_out;
    unsigned int* wd    = (unsigned int*)d_ws;

    unsigned int* hist = wd + HIST_DW;
    double*       bins = (double*)(wd + BINS_DW);
    float*        conf = (float*)(wd + CONF_DW);

    k1_rowmax<<<2048, 256, 0, stream>>>(x, labels, conf, wd);
    k2_hist  <<<128, 512, 0, stream>>>(conf, hist);
    k3_accum <<<512, 256, 0, stream>>>(conf, hist, bins);
    k4_final <<<1, 64, 0, stream>>>(bins, out);
}

// Round 16
// 115.733 us; speedup vs baseline: 1.7938x; 1.0742x over previous
//
#include <hip/hip_runtime.h>
#include <hip/hip_bf16.h>
#include <math.h>
#include <stdint.h>

#define NROWS 1000000
#define NCOLS 100
#define NBINS 20
#define NB    19       // bin boundaries
#define W     50000u   // rows per bin
#define NH    2049     // buckets: 0 = catch-all (<0.5), 1..2048 = [0.5,1) in 2^-12 steps

// ---------- ws layout (dword offsets) ----------
#define HIST_DW 0u       // len 2052
#define BINS_DW 2052u    // len 80 dw = 40 doubles (byte 8208, 8-aligned)
#define ZERO_DW 2132u    // hist+bins zeroed inside k1
#define CONF_DW 2136u    // len 1000000 (byte 8544 = 534*16, 16B-aligned); sign bit = accuracy

// async DMA global->LDS, width 16B: lds dest = (wave-uniform base) + lane*16
#define GLOAD_LDS16(g, l) __builtin_amdgcn_global_load_lds(                    \
    (const __attribute__((address_space(1))) void*)(g),                        \
    (__attribute__((address_space(3))) void*)(l), 16, 0, 0)

__device__ __forceinline__ unsigned int bucket_of(unsigned int bits) {
    // bits = positive-f32 pattern. conf < 0.5 -> 0 (catch-all).
    if (bits < 0x3F000000u) return 0u;
    unsigned int t = (bits >> 12) - 258048u + 1u;   // 1..2048 for [0.5,1)
    return t > 2048u ? 2048u : t;
}

// ---------- K1: LDS-staged row max/argmax via global_load_lds --------------
// r15 post-mortem: labels prefetch null. Last documented staging lever:
// global_load_lds width=16 (compiler never auto-emits it; +67% on GEMM
// staging, m193). Replaces global->VGPR->ds_write with direct async DMA.
// LDS layout is linear so the wave-uniform-base+lane*16 dest rule matches
// exactly: iter i, wave w, lane l -> ldsx4 + i*256 + 64w + l.
__global__ __launch_bounds__(256) void k1_rowmax(const float* __restrict__ x,
                                                 const int* __restrict__ labels,
                                                 float* __restrict__ conf,
                                                 unsigned int* __restrict__ zero_region) {
    __shared__ float4 ldsx4[1600];                 // 64 rows x 25 float4, linear
    __shared__ unsigned long long ldsk[64];
    const float* ldsx = (const float*)ldsx4;
    int tid = threadIdx.x;
    int gtid = blockIdx.x * 256 + tid;
    if (gtid < (int)ZERO_DW) zero_region[gtid] = 0u;   // hist + bins

    const int NTILES = NROWS / 64;  // 15625
    const float4* xb = reinterpret_cast<const float4*>(x);
    for (int tile = blockIdx.x; tile < NTILES; tile += gridDim.x) {
        // --- stage: 1600 float4, direct-to-LDS DMA (no VGPR round-trip) ---
        const float4* src = xb + (size_t)tile * 1600;
        int lab = 0;
        if (tid < 64) lab = labels[tile * 64 + tid];   // overlaps with DMA issue
        int wbase = tid & 192;                         // wave-uniform within block
        #pragma unroll
        for (int i = 0; i < 6; i++) {
            int v = i * 256 + tid;
            GLOAD_LDS16(src + v, ldsx4 + i * 256 + wbase);
        }
        if (tid < 64) GLOAD_LDS16(src + 1536 + tid, ldsx4 + 1536);  // tail, wave 0
        if (tid < 64) ldsk[tid] = 0ull;
        __syncthreads();                               // drains vmcnt (DMA done)
        // --- reduce: thread = (row r, quarter q); dword addr = 25*tid+k ---
        int r = tid >> 2, q = tid & 3;
        const float* rowp = ldsx + r * 100 + q * 25;
        float best = rowp[0]; int bi = 0;
        #pragma unroll
        for (int k = 1; k < 25; k++) {
            float vv = rowp[k];
            if (vv > best) { best = vv; bi = k; }
        }
        unsigned long long key =
            ((unsigned long long)__float_as_uint(best) << 32)
            | (unsigned int)(NCOLS - (q * 25 + bi));   // bigger low32 = smaller idx
        atomicMax(&ldsk[r], key);
        __syncthreads();
        if (tid < 64) {
            unsigned long long kk = ldsk[tid];
            unsigned int bits = (unsigned int)(kk >> 32);
            int idx = NCOLS - (int)(kk & 0xFFFFFFFFu);
            if (idx == lab) bits |= 0x80000000u;
            conf[tile * 64 + tid] = __uint_as_float(bits);
        }
        __syncthreads();   // ldsx/ldsk reused next tile
    }
}

// ---------- K2: 2049-bucket histogram, per-block LDS ----------
__global__ __launch_bounds__(512) void k2_hist(const float* __restrict__ conf,
                                               unsigned int* __restrict__ hist) {
    __shared__ unsigned int lh[NH];
    for (int i = threadIdx.x; i < NH; i += 512) lh[i] = 0u;
    __syncthreads();
    const uint4* c4 = reinterpret_cast<const uint4*>(conf);
    int stride = gridDim.x * 512;
    for (int i = blockIdx.x * 512 + threadIdx.x; i < NROWS / 4; i += stride) {
        uint4 v = c4[i];
        atomicAdd(&lh[bucket_of(v.x & 0x7FFFFFFFu)], 1u);
        atomicAdd(&lh[bucket_of(v.y & 0x7FFFFFFFu)], 1u);
        atomicAdd(&lh[bucket_of(v.z & 0x7FFFFFFFu)], 1u);
        atomicAdd(&lh[bucket_of(v.w & 0x7FFFFFFFu)], 1u);
    }
    __syncthreads();
    for (int i = threadIdx.x; i < NH; i += 512) {
        unsigned int c = lh[i];
        if (c) atomicAdd(&hist[i], c);
    }
}

// ---------- K3: per-block redundant scan+bounds, then split-accumulate ----
__global__ __launch_bounds__(256) void k3_accum(const float* __restrict__ conf,
                                                const unsigned int* __restrict__ hist,
                                                double* __restrict__ bins) {
    __shared__ unsigned int ptab[NH];   // prefix, later |= (slot+1)<<24 on boundary buckets
    __shared__ unsigned int s[256];
    __shared__ unsigned int bndS[NB];
    __shared__ float sFr[NB];
    __shared__ float sc[4][NBINS], sa[4][NBINS];
    int tid = threadIdx.x;

    // --- scan hist (2049) into ptab ---
    unsigned int loc[9];
    unsigned int tot = 0;
    int base = tid * 9;
    #pragma unroll
    for (int k = 0; k < 9; k++) {
        int idx = base + k;
        unsigned int v = (idx < NH) ? hist[idx] : 0u;
        loc[k] = tot; tot += v;
    }
    s[tid] = tot; __syncthreads();
    for (int off = 1; off < 256; off <<= 1) {
        unsigned int v = (tid >= off) ? s[tid - off] : 0u;
        __syncthreads();
        s[tid] += v;
        __syncthreads();
    }
    unsigned int excl = s[tid] - tot;
    #pragma unroll
    for (int k = 0; k < 9; k++) {
        int idx = base + k;
        if (idx < NH) ptab[idx] = excl + loc[k];
    }
    for (int i = tid; i < 4 * NBINS; i += 256) { (&sc[0][0])[i] = 0.f; (&sa[0][0])[i] = 0.f; }
    __syncthreads();

    // --- phase A: locate boundaries on the CLEAN prefix, save fr ---
    if (tid < NB) {
        unsigned int r = (unsigned int)(tid + 1) * W;
        int lo = 0, hi = NH - 1;
        while (lo < hi) {
            int mid = (lo + hi + 1) >> 1;
            if (ptab[mid] <= r) lo = mid; else hi = mid - 1;
        }
        unsigned int p = ptab[lo];
        if (p < r) {
            unsigned int cnt = ((lo + 1 < NH) ? ptab[lo + 1] : (unsigned int)NROWS) - p;
            bndS[tid] = (unsigned int)lo;
            sFr[tid]  = (float)(r - p) / (float)cnt;
        } else {
            bndS[tid] = 0xFFFFFFFFu;
        }
    }
    __syncthreads();
    // --- phase B: mark boundary buckets ---
    if (tid < NB && bndS[tid] != 0xFFFFFFFFu)
        ptab[bndS[tid]] |= (unsigned int)(tid + 1) << 24;
    __syncthreads();

    // --- main pass ---
    int wid = tid >> 6;
    const uint4* c4 = reinterpret_cast<const uint4*>(conf);
    int stride = gridDim.x * 256;
    for (int i = blockIdx.x * 256 + tid; i < NROWS / 4; i += stride) {
        uint4 q = c4[i];
        unsigned int bs[4] = { q.x, q.y, q.z, q.w };
        #pragma unroll
        for (int j = 0; j < 4; j++) {
            unsigned int raw = bs[j];
            float a = (float)(raw >> 31);
            unsigned int bits = raw & 0x7FFFFFFFu;
            float c = __uint_as_float(bits);
            unsigned int e = ptab[bucket_of(bits)];
            unsigned int t = e >> 24;
            if (t == 0u) {
                unsigned int bin = (e & 0xFFFFFFu) / W;
                atomicAdd(&sc[wid][bin], c); atomicAdd(&sa[wid][bin], a);
            } else {
                float fr = sFr[t - 1];
                atomicAdd(&sc[wid][t - 1], c * fr);
                atomicAdd(&sc[wid][t],     c * (1.f - fr));
                atomicAdd(&sa[wid][t - 1], a * fr);
                atomicAdd(&sa[wid][t],     a * (1.f - fr));
            }
        }
    }
    __syncthreads();
    if (tid < NBINS) {
        float tc = sc[0][tid] + sc[1][tid] + sc[2][tid] + sc[3][tid];
        float ta = sa[0][tid] + sa[1][tid] + sa[2][tid] + sa[3][tid];
        atomicAdd(&bins[tid],         (double)tc);
        atomicAdd(&bins[NBINS + tid], (double)ta);
    }
}

// ---------- K4: finalize ----------
__global__ __launch_bounds__(64) void k4_final(const double* __restrict__ bins,
                                               float* __restrict__ out) {
    if (threadIdx.x == 0) {
        double ece = 0.0;
        for (int b = 0; b < NBINS; b++) {
            double avc = bins[b] / (double)W;
            double ava = bins[NBINS + b] / (double)W;
            ece += fabs(avc - ava);
            out[1 + b] = (float)ava;
        }
        out[0] = (float)(ece * ((double)W / (double)NROWS));
    }
}

extern "C" void kernel_launch(void* const* d_in, const int* in_sizes, int n_in,
                              void* d_out, int out_size, void* d_ws, size_t ws_size,
                              hipStream_t stream) {
    const float* x      = (const float*)d_in[0];
    const int*   labels = (const int*)d_in[1];
    float*       out    = (float*)d_out;
    unsigned int* wd    = (unsigned int*)d_ws;

    unsigned int* hist = wd + HIST_DW;
    double*       bins = (double*)(wd + BINS_DW);
    float*        conf = (float*)(wd + CONF_DW);

    k1_rowmax<<<2048, 256, 0, stream>>>(x, labels, conf, wd);
    k2_hist  <<<128, 512, 0, stream>>>(conf, hist);
    k3_accum <<<512, 256, 0, stream>>>(conf, hist, bins);
    k4_final <<<1, 64, 0, stream>>>(bins, out);
}

// Round 17
// 115.594 us; speedup vs baseline: 1.7959x; 1.0012x over previous
//
#include <hip/hip_runtime.h>
#include <hip/hip_bf16.h>
#include <math.h>
#include <stdint.h>

#define NROWS 1000000
#define NCOLS 100
#define NBINS 20
#define NB    19       // bin boundaries
#define W     50000u   // rows per bin
#define NH    2049     // buckets: 0 = catch-all (<0.5), 1..2048 = [0.5,1) in 2^-12 steps

// ---------- ws layout (dword offsets) ----------
#define HIST_DW 0u       // len 2052
#define BINS_DW 2052u    // len 80 dw = 40 doubles (byte 8208, 8-aligned)
#define ZERO_DW 2132u    // hist+bins zeroed inside k1
#define CONF_DW 2136u    // len 1000000 (byte 8544 = 534*16, 16B-aligned); sign bit = accuracy

// async DMA global->LDS, width 16B: lds dest = (wave-uniform base) + lane*16
#define GLOAD_LDS16(g, l) __builtin_amdgcn_global_load_lds(                    \
    (const __attribute__((address_space(1))) void*)(g),                        \
    (__attribute__((address_space(3))) void*)(l), 16, 0, 0)

__device__ __forceinline__ unsigned int bucket_of(unsigned int bits) {
    // bits = positive-f32 pattern. conf < 0.5 -> 0 (catch-all).
    if (bits < 0x3F000000u) return 0u;
    unsigned int t = (bits >> 12) - 258048u + 1u;   // 1..2048 for [0.5,1)
    return t > 2048u ? 2048u : t;
}

// ---------- K1: double-buffered DMA staging + counted vmcnt (T3/T4) --------
// r16: global_load_lds got k1 to ~75us; residual = __syncthreads' implicit
// vmcnt(0) drain per tile (m97 stall). This version: 2 LDS buffers; issue
// tile t+1's DMA, then inline-asm s_waitcnt vmcnt(8) (only t's 8 ops must
// retire; t+1's stay IN FLIGHT across the raw s_barrier), reduce t, raw
// barrier, swap. Uniform 8 vmem ops/wave/tile: 6 full DMA + 1 masked
// 16-lane tail DMA + 1 labels load (+1 conf store, retired in-order before
// the count). ldsk atomics -> shfl_xor over the row's 4 quarter-lanes.
__global__ __launch_bounds__(256) void k1_rowmax(const float* __restrict__ x,
                                                 const int* __restrict__ labels,
                                                 float* __restrict__ conf,
                                                 unsigned int* __restrict__ zero_region) {
    __shared__ float4 ldsx4[3200];                 // two 1600-f4 buffers
    int tid = threadIdx.x;
    int gtid = blockIdx.x * 256 + tid;
    if (gtid < (int)ZERO_DW) zero_region[gtid] = 0u;   // hist + bins

    const int NTILES = NROWS / 64;  // 15625
    const float4* xb = reinterpret_cast<const float4*>(x);
    int lane = tid & 63;
    int w    = tid >> 6;
    int lab_next = 0, lab_cur = 0;

    float4* bufA = ldsx4;          // current (being reduced)
    float4* bufB = ldsx4 + 1600;   // being filled

    // issue = 8 vmem ops per wave, uniform: 6 full DMA + 1 tail DMA + 1 label
#define K1_ISSUE(t, buf)                                                       \
    do {                                                                       \
        const float4* src_ = xb + (size_t)(t) * 1600;                          \
        _Pragma("unroll")                                                      \
        for (int i_ = 0; i_ < 6; i_++)                                         \
            GLOAD_LDS16(src_ + i_ * 256 + tid, (buf) + i_ * 256 + (tid & 192));\
        if (lane < 16)                                                         \
            GLOAD_LDS16(src_ + 1536 + 16 * w + lane, (buf) + 1536 + 16 * w);   \
        if ((tid & 3) == 0) lab_next = labels[(t) * 64 + (tid >> 2)];          \
    } while (0)

    int tile = blockIdx.x;
    if (tile < NTILES) K1_ISSUE(tile, bufA);

    while (tile < NTILES) {
        lab_cur = lab_next;
        int nxt = tile + gridDim.x;
        if (nxt < NTILES) {
            K1_ISSUE(nxt, bufB);
            asm volatile("s_waitcnt vmcnt(8)" ::: "memory");   // cur buffer done; next in flight
        } else {
            asm volatile("s_waitcnt vmcnt(0)" ::: "memory");
        }
        __builtin_amdgcn_sched_barrier(0);
        __builtin_amdgcn_s_barrier();                          // all waves' cur-slices landed

        // --- reduce: thread = (row r = tid>>2, quarter q = tid&3) ---
        const float* rowp = (const float*)bufA + (tid >> 2) * 100 + (tid & 3) * 25;
        float best = rowp[0]; int bi = 0;
        #pragma unroll
        for (int k = 1; k < 25; k++) {
            float vv = rowp[k];
            if (vv > best) { best = vv; bi = k; }
        }
        bi += (tid & 3) * 25;                                  // global column index
        #pragma unroll
        for (int mask = 1; mask <= 2; mask <<= 1) {
            float ov = __shfl_xor(best, mask);
            int   oi = __shfl_xor(bi,   mask);
            if (ov > best || (ov == best && oi < bi)) { best = ov; bi = oi; }
        }
        if ((tid & 3) == 0) {
            unsigned int bits = __float_as_uint(best);
            if (bi == lab_cur) bits |= 0x80000000u;
            conf[tile * 64 + (tid >> 2)] = __uint_as_float(bits);
        }
        __builtin_amdgcn_s_barrier();                          // cur buffer free for overwrite

        float4* tmp = bufA; bufA = bufB; bufB = tmp;
        tile = nxt;
    }
#undef K1_ISSUE
}

// ---------- K2: 2049-bucket histogram, per-block LDS ----------
__global__ __launch_bounds__(512) void k2_hist(const float* __restrict__ conf,
                                               unsigned int* __restrict__ hist) {
    __shared__ unsigned int lh[NH];
    for (int i = threadIdx.x; i < NH; i += 512) lh[i] = 0u;
    __syncthreads();
    const uint4* c4 = reinterpret_cast<const uint4*>(conf);
    int stride = gridDim.x * 512;
    for (int i = blockIdx.x * 512 + threadIdx.x; i < NROWS / 4; i += stride) {
        uint4 v = c4[i];
        atomicAdd(&lh[bucket_of(v.x & 0x7FFFFFFFu)], 1u);
        atomicAdd(&lh[bucket_of(v.y & 0x7FFFFFFFu)], 1u);
        atomicAdd(&lh[bucket_of(v.z & 0x7FFFFFFFu)], 1u);
        atomicAdd(&lh[bucket_of(v.w & 0x7FFFFFFFu)], 1u);
    }
    __syncthreads();
    for (int i = threadIdx.x; i < NH; i += 512) {
        unsigned int c = lh[i];
        if (c) atomicAdd(&hist[i], c);
    }
}

// ---------- K3: per-block redundant scan+bounds, then split-accumulate ----
__global__ __launch_bounds__(256) void k3_accum(const float* __restrict__ conf,
                                                const unsigned int* __restrict__ hist,
                                                double* __restrict__ bins) {
    __shared__ unsigned int ptab[NH];   // prefix, later |= (slot+1)<<24 on boundary buckets
    __shared__ unsigned int s[256];
    __shared__ unsigned int bndS[NB];
    __shared__ float sFr[NB];
    __shared__ float sc[4][NBINS], sa[4][NBINS];
    int tid = threadIdx.x;

    // --- scan hist (2049) into ptab ---
    unsigned int loc[9];
    unsigned int tot = 0;
    int base = tid * 9;
    #pragma unroll
    for (int k = 0; k < 9; k++) {
        int idx = base + k;
        unsigned int v = (idx < NH) ? hist[idx] : 0u;
        loc[k] = tot; tot += v;
    }
    s[tid] = tot; __syncthreads();
    for (int off = 1; off < 256; off <<= 1) {
        unsigned int v = (tid >= off) ? s[tid - off] : 0u;
        __syncthreads();
        s[tid] += v;
        __syncthreads();
    }
    unsigned int excl = s[tid] - tot;
    #pragma unroll
    for (int k = 0; k < 9; k++) {
        int idx = base + k;
        if (idx < NH) ptab[idx] = excl + loc[k];
    }
    for (int i = tid; i < 4 * NBINS; i += 256) { (&sc[0][0])[i] = 0.f; (&sa[0][0])[i] = 0.f; }
    __syncthreads();

    // --- phase A: locate boundaries on the CLEAN prefix, save fr ---
    if (tid < NB) {
        unsigned int r = (unsigned int)(tid + 1) * W;
        int lo = 0, hi = NH - 1;
        while (lo < hi) {
            int mid = (lo + hi + 1) >> 1;
            if (ptab[mid] <= r) lo = mid; else hi = mid - 1;
        }
        unsigned int p = ptab[lo];
        if (p < r) {
            unsigned int cnt = ((lo + 1 < NH) ? ptab[lo + 1] : (unsigned int)NROWS) - p;
            bndS[tid] = (unsigned int)lo;
            sFr[tid]  = (float)(r - p) / (float)cnt;
        } else {
            bndS[tid] = 0xFFFFFFFFu;
        }
    }
    __syncthreads();
    // --- phase B: mark boundary buckets ---
    if (tid < NB && bndS[tid] != 0xFFFFFFFFu)
        ptab[bndS[tid]] |= (unsigned int)(tid + 1) << 24;
    __syncthreads();

    // --- main pass ---
    int wid = tid >> 6;
    const uint4* c4 = reinterpret_cast<const uint4*>(conf);
    int stride = gridDim.x * 256;
    for (int i = blockIdx.x * 256 + tid; i < NROWS / 4; i += stride) {
        uint4 q = c4[i];
        unsigned int bs[4] = { q.x, q.y, q.z, q.w };
        #pragma unroll
        for (int j = 0; j < 4; j++) {
            unsigned int raw = bs[j];
            float a = (float)(raw >> 31);
            unsigned int bits = raw & 0x7FFFFFFFu;
            float c = __uint_as_float(bits);
            unsigned int e = ptab[bucket_of(bits)];
            unsigned int t = e >> 24;
            if (t == 0u) {
                unsigned int bin = (e & 0xFFFFFFu) / W;
                atomicAdd(&sc[wid][bin], c); atomicAdd(&sa[wid][bin], a);
            } else {
                float fr = sFr[t - 1];
                atomicAdd(&sc[wid][t - 1], c * fr);
                atomicAdd(&sc[wid][t],     c * (1.f - fr));
                atomicAdd(&sa[wid][t - 1], a * fr);
                atomicAdd(&sa[wid][t],     a * (1.f - fr));
            }
        }
    }
    __syncthreads();
    if (tid < NBINS) {
        float tc = sc[0][tid] + sc[1][tid] + sc[2][tid] + sc[3][tid];
        float ta = sa[0][tid] + sa[1][tid] + sa[2][tid] + sa[3][tid];
        atomicAdd(&bins[tid],         (double)tc);
        atomicAdd(&bins[NBINS + tid], (double)ta);
    }
}

// ---------- K4: finalize ----------
__global__ __launch_bounds__(64) void k4_final(const double* __restrict__ bins,
                                               float* __restrict__ out) {
    if (threadIdx.x == 0) {
        double ece = 0.0;
        for (int b = 0; b < NBINS; b++) {
            double avc = bins[b] / (double)W;
            double ava = bins[NBINS + b] / (double)W;
            ece += fabs(avc - ava);
            out[1 + b] = (float)ava;
        }
        out[0] = (float)(ece * ((double)W / (double)NROWS));
    }
}

extern "C" void kernel_launch(void* const* d_in, const int* in_sizes, int n_in,
                              void* d_out, int out_size, void* d_ws, size_t ws_size,
                              hipStream_t stream) {
    const float* x      = (const float*)d_in[0];
    const int*   labels = (const int*)d_in[1];
    float*       out    = (float*)d_out;
    unsigned int* wd    = (unsigned int*)d_ws;

    unsigned int* hist = wd + HIST_DW;
    double*       bins = (double*)(wd + BINS_DW);
    float*        conf = (float*)(wd + CONF_DW);

    k1_rowmax<<<2048, 256, 0, stream>>>(x, labels, conf, wd);
    k2_hist  <<<128, 512, 0, stream>>>(conf, hist);
    k3_accum <<<512, 256, 0, stream>>>(conf, hist, bins);
    k4_final <<<1, 64, 0, stream>>>(bins, out);
}